// Round 18
// baseline (13.830 us; speedup 1.0000x reference)
//
#include <hip/hip_runtime.h>

#define DEV __device__ __forceinline__

// ============================================================================
// Transfer-matrix (MPS) formulation, Hermitian-compressed. One THREAD/sample.
// [R16-verified pipeline]
//   psi_f = PHI . L2 . PHI . (prod-state after encode+L1)
//   observables conjugated through 2nd CNOT chain:
//     Z_w -> Z_0..Z_w (prefix),  X_w -> X_w X_{w+1} (w<=8), X_9 -> X_9
//   through L2: Z -> ZM_v = U2^dag Z U2, X -> XM_v (Hermitian 2x2)
//   per-step transfer = congruence G^dag H G then Hadamard with M,
//     G = [[g0,g1],[g1,g0]], g = U1 @ (cos,sin).
// R17 bug (fixed here): A's identity transfer must Hadamard with I, i.e.
// ZERO the congruence's off-diagonal (R16 set nA01=nA10=0 explicitly).
// congr_diag applies that analytically (and saves the o-computation).
// ============================================================================

struct cpx { float r, i; };
DEV cpx cmul (cpx a, cpx b) { return {a.r*b.r - a.i*b.i, a.r*b.i + a.i*b.r}; }
DEV cpx cjmul(cpx a, cpx b) { return {a.r*b.r + a.i*b.i, a.r*b.i - a.i*b.r}; } // conj(a)*b
DEV cpx cadd (cpx a, cpx b) { return {a.r + b.r, a.i + b.i}; }
DEV cpx csc  (cpx a, float s) { return {a.r*s, a.i*s}; }
DEV cpx cconj(cpx a) { return {a.r, -a.i}; }
DEV float reCj(cpx a, cpx b) { return a.r*b.r + a.i*b.i; }  // Re(conj(a)*b)

// Hermitian 2x2: [[d0, o],[conj(o), d1]]
struct herm { float d0, d1; cpx o; };

// full congruence H' = G^dag H G
DEV herm congr(const herm& H, cpx g0, cpx g1) {
  cpx t0 = cadd(csc(g0, H.d0), cmul(H.o, g1));            // (H G)[0][0]
  cpx t1 = cadd(csc(g1, H.d0), cmul(H.o, g0));            // (H G)[0][1]
  cpx ob = cconj(H.o);
  cpx s0 = cadd(cmul(ob, g0), csc(g1, H.d1));             // (H G)[1][0]
  cpx s1 = cadd(cmul(ob, g1), csc(g0, H.d1));             // (H G)[1][1]
  herm R;
  R.d0 = reCj(g0, t0) + reCj(g1, s0);
  R.d1 = reCj(g1, t1) + reCj(g0, s1);
  R.o  = cadd(cjmul(g0, t1), cjmul(g1, s1));
  return R;
}

// congruence followed by Hadamard-with-identity: only the diagonal survives
DEV void congr_diag(const herm& H, cpx g0, cpx g1, float& d0, float& d1) {
  cpx t0 = cadd(csc(g0, H.d0), cmul(H.o, g1));
  cpx t1 = cadd(csc(g1, H.d0), cmul(H.o, g0));
  cpx ob = cconj(H.o);
  cpx s0 = cadd(cmul(ob, g0), csc(g1, H.d1));
  cpx s1 = cadd(cmul(ob, g1), csc(g0, H.d1));
  d0 = reCj(g0, t0) + reCj(g1, s0);
  d1 = reCj(g1, t1) + reCj(g0, s1);
}

DEV void make_u(const float* __restrict__ pp, float (&u)[8]) {
  // PennyLane Rot = RZ(om) @ RY(th) @ RZ(ph)   [R13-verified]
  float ph = pp[0], th = pp[1], om = pp[2];
  float s, c;   __sincosf(0.5f * th, &s, &c);
  float sa, ca; __sincosf(0.5f * (ph + om), &sa, &ca);
  float sb, cb; __sincosf(0.5f * (ph - om), &sb, &cb);
  u[0] = c * ca;  u[1] = -c * sa;   // u00
  u[2] = -s * cb; u[3] = -s * sb;   // u01
  u[4] = s * cb;  u[5] = -s * sb;   // u10
  u[6] = c * ca;  u[7] = c * sa;    // u11
}

__global__ __launch_bounds__(64) void qreg_kernel(
    const float* __restrict__ x,      // (B, 10)
    const float* __restrict__ params, // (60,)
    const float* __restrict__ hw,     // (20,)
    const float* __restrict__ hb,     // (1,)
    float* __restrict__ out,          // (B,)
    int Bn) {
  const int tid = threadIdx.x;
  const int b = blockIdx.x * 64 + tid;
  const int br = (b < Bn) ? b : (Bn - 1);

  // issue x loads before the barrier (float2, 8B-aligned)
  float xv[10];
  {
    const float2* xp = reinterpret_cast<const float2*>(x + br * 10);
#pragma unroll
    for (int k = 0; k < 5; ++k) {
      float2 t = xp[k];
      xv[2 * k] = t.x; xv[2 * k + 1] = t.y;
    }
  }

  __shared__ __align__(16) float U1[10][8];  // layer-1 Rot matrices
  __shared__ __align__(16) float ZMs[10][4]; // {m00, m11, m01r, m01i}
  __shared__ __align__(16) float XMs[10][4]; // unscaled (pair starts)
  __shared__ __align__(16) float CLs[10][4]; // hw[9+v]*XM[v]  (closures, v>=1)

  if (tid < 10) {
    float u[8]; make_u(params + (10 + tid) * 3, u);
    cpx u00 = {u[0], u[1]}, u01 = {u[2], u[3]};
    cpx u10 = {u[4], u[5]}, u11 = {u[6], u[7]};
    float n00 = u00.r*u00.r + u00.i*u00.i, n01 = u01.r*u01.r + u01.i*u01.i;
    float n10 = u10.r*u10.r + u10.i*u10.i, n11 = u11.r*u11.r + u11.i*u11.i;
    cpx zm01 = cadd(cjmul(u00, u01), csc(cjmul(u10, u11), -1.f));
    ZMs[tid][0] = n00 - n10; ZMs[tid][1] = n01 - n11;
    ZMs[tid][2] = zm01.r;    ZMs[tid][3] = zm01.i;
    cpx xm01 = cadd(cjmul(u00, u11), cjmul(u10, u01));
    float x00 = 2.f * (u00.r*u10.r + u00.i*u10.i);
    float x11 = 2.f * (u01.r*u11.r + u01.i*u11.i);
    XMs[tid][0] = x00; XMs[tid][1] = x11;
    XMs[tid][2] = xm01.r; XMs[tid][3] = xm01.i;
    const float w = (tid >= 1) ? hw[9 + tid] : 0.f;
    CLs[tid][0] = w * x00; CLs[tid][1] = w * x11;
    CLs[tid][2] = w * xm01.r; CLs[tid][3] = w * xm01.i;
  } else if (tid >= 16 && tid < 26) {
    const int w = tid - 16;
    float u[8]; make_u(params + w * 3, u);
#pragma unroll
    for (int k = 0; k < 8; ++k) U1[w][k] = u[k];
  }
  __syncthreads();
  if (b >= Bn) return;

  herm A{0.f, 0.f, {0.f, 0.f}};        // accumulator
  herm Z{1.f, 0.f, {0.f, 0.f}};        // Z-prefix vector
  herm P{0.f, 0.f, {0.f, 0.f}};        // pending X pair
  float f0 = 1.f, f1 = 0.f;            // all-I vector (real diagonal)

#pragma unroll
  for (int v = 0; v < 10; ++v) {
    float sn, cs; __sincosf(0.5f * xv[v], &sn, &cs);
    cpx g0 = {U1[v][0]*cs + U1[v][2]*sn, U1[v][1]*cs + U1[v][3]*sn};
    cpx g1 = {U1[v][4]*cs + U1[v][6]*sn, U1[v][5]*cs + U1[v][7]*sn};
    const float n0 = g0.r*g0.r + g0.i*g0.i, n1 = g1.r*g1.r + g1.i*g1.i;
    const cpx xm01 = {XMs[v][2], XMs[v][3]};

    // ---- A: identity transfer = congruence + Hadamard(I) -> diagonal only
    herm nA;
    congr_diag(A, g0, g1, nA.d0, nA.d1);
    nA.o = (cpx){0.f, 0.f};

    // ---- complete pending X_{v-1}: CL[v] .* (G^dag P G), add into A ----
    if (v >= 1) {
      herm q = congr(P, g0, g1);
      nA.d0 += CLs[v][0] * q.d0;
      nA.d1 += CLs[v][1] * q.d1;
      nA.o = cadd(nA.o, cmul((cpx){CLs[v][2], CLs[v][3]}, q.o));
    }

    // ---- start X_v from f (S = G^dag diag(f) G), P = XM .* S ----
    const float S00 = n0 * f0 + n1 * f1;
    const float S11 = n1 * f0 + n0 * f1;
    {
      cpx h01 = cjmul(g0, g1);
      cpx S01 = {(f0 + f1) * h01.r, (f0 - f1) * h01.i};
      P.d0 = S00 * XMs[v][0];
      P.d1 = S11 * XMs[v][1];
      P.o  = cmul(xm01, S01);
    }

    // ---- zf: congruence, Hadamard ZM, weighted snapshot into A ----
    {
      herm y = congr(Z, g0, g1);
      Z.d0 = y.d0 * ZMs[v][0];
      Z.d1 = y.d1 * ZMs[v][1];
      Z.o  = cmul((cpx){ZMs[v][2], ZMs[v][3]}, y.o);
      const float w = hw[v];
      nA.d0 += w * Z.d0; nA.d1 += w * Z.d1;
      nA.o = cadd(nA.o, csc(Z.o, w));
    }

    A = nA;
    f0 = S00; f1 = S11;  // f-update == S diagonal (reuse)
  }

  // X_9 single-wire: P after step 9 is the complete feature (weight hw[19]).
  const float res = A.d0 + A.d1 + 2.f * A.o.r
                  + hw[19] * (P.d0 + P.d1 + 2.f * P.o.r)
                  + hb[0];
  out[b] = res;
}

extern "C" void kernel_launch(void* const* d_in, const int* in_sizes, int n_in,
                              void* d_out, int out_size, void* d_ws, size_t ws_size,
                              hipStream_t stream) {
  const float* x      = (const float*)d_in[0];
  const float* params = (const float*)d_in[1];
  const float* hw     = (const float*)d_in[2];
  const float* hb     = (const float*)d_in[3];
  float* out = (float*)d_out;
  const int B = in_sizes[0] / 10;
  const int blocks = (B + 63) / 64;  // one THREAD per sample
  qreg_kernel<<<blocks, 64, 0, stream>>>(x, params, hw, hb, out, B);
}

// Round 19
// 12.251 us; speedup vs baseline: 1.1289x; 1.1289x over previous
//
#include <hip/hip_runtime.h>

#define DEV __device__ __forceinline__

// ============================================================================
// Transfer-matrix (MPS) formulation. One THREAD per sample.
// [R16-VERIFIED dataflow, 12.1 us measured — reverted from R18's Hermitian
//  compression which regressed to 13.8 us (longer serial dependency chains;
//  kernel is launch+latency bound at 64 waves total, not issue-bound).]
// Only addition vs R16: float2 x-prefetch issued before the barrier (R18-safe).
//
// Pipeline: psi_f = PHI . L2 . PHI . (prod-state after encode+L1)
//   - observables conjugated through the 2nd CNOT chain:
//       Z_w -> Z_0..Z_w (prefix),  X_w -> X_w X_{w+1} (w<=8), X_9 -> X_9
//   - through L2: Z -> ZM_v = U2^dag Z U2, X -> XM_v (2x2 Hermitian)
//   - expectation = 4-state transfer contraction (f, zf, px, A streams).
// ============================================================================

struct cpx { float r, i; };
DEV cpx cmul (cpx a, cpx b) { return {a.r*b.r - a.i*b.i, a.r*b.i + a.i*b.r}; }
DEV cpx cjmul(cpx a, cpx b) { return {a.r*b.r + a.i*b.i, a.r*b.i - a.i*b.r}; } // conj(a)*b
DEV cpx cadd (cpx a, cpx b) { return {a.r + b.r, a.i + b.i}; }
DEV cpx csc  (cpx a, float s) { return {a.r*s, a.i*s}; }
DEV cpx cconj(cpx a) { return {a.r, -a.i}; }

DEV void make_u(const float* __restrict__ pp, float (&u)[8]) {
  // PennyLane Rot = RZ(om) @ RY(th) @ RZ(ph)   [R13-verified]
  float ph = pp[0], th = pp[1], om = pp[2];
  float s, c;   __sincosf(0.5f * th, &s, &c);
  float sa, ca; __sincosf(0.5f * (ph + om), &sa, &ca);
  float sb, cb; __sincosf(0.5f * (ph - om), &sb, &cb);
  u[0] = c * ca;  u[1] = -c * sa;   // u00
  u[2] = -s * cb; u[3] = -s * sb;   // u01
  u[4] = s * cb;  u[5] = -s * sb;   // u10
  u[6] = c * ca;  u[7] = c * sa;    // u11
}

__global__ __launch_bounds__(64) void qreg_kernel(
    const float* __restrict__ x,      // (B, 10)
    const float* __restrict__ params, // (60,)
    const float* __restrict__ hw,     // (20,)
    const float* __restrict__ hb,     // (1,)
    float* __restrict__ out,          // (B,)
    int Bn) {
  const int tid = threadIdx.x;
  const int b = blockIdx.x * 64 + tid;
  const int br = (b < Bn) ? b : (Bn - 1);

  // issue x loads before the barrier (float2, 8B-aligned) — hides HBM latency
  float xv[10];
  {
    const float2* xp = reinterpret_cast<const float2*>(x + br * 10);
#pragma unroll
    for (int k = 0; k < 5; ++k) {
      float2 t = xp[k];
      xv[2 * k] = t.x; xv[2 * k + 1] = t.y;
    }
  }

  __shared__ __align__(16) float U1[10][8];  // layer-1 Rot matrices
  __shared__ __align__(16) float ZM[10][4];  // {m00, m11, m01r, m01i} (Hermitian)
  __shared__ __align__(16) float XM[10][4];

  if (tid < 10) {
    // layer-2 matrices -> conjugated Pauli observables
    float u[8]; make_u(params + (10 + tid) * 3, u);
    cpx u00 = {u[0], u[1]}, u01 = {u[2], u[3]};
    cpx u10 = {u[4], u[5]}, u11 = {u[6], u[7]};
    float n00 = u00.r*u00.r + u00.i*u00.i, n01 = u01.r*u01.r + u01.i*u01.i;
    float n10 = u10.r*u10.r + u10.i*u10.i, n11 = u11.r*u11.r + u11.i*u11.i;
    cpx zm01 = cadd(cjmul(u00, u01), csc(cjmul(u10, u11), -1.f));
    ZM[tid][0] = n00 - n10; ZM[tid][1] = n01 - n11;
    ZM[tid][2] = zm01.r;    ZM[tid][3] = zm01.i;
    cpx xm01 = cadd(cjmul(u00, u11), cjmul(u10, u01));
    XM[tid][0] = 2.f * (u00.r*u10.r + u00.i*u10.i);
    XM[tid][1] = 2.f * (u01.r*u11.r + u01.i*u11.i);
    XM[tid][2] = xm01.r; XM[tid][3] = xm01.i;
  } else if (tid >= 16 && tid < 26) {
    const int w = tid - 16;
    float u[8]; make_u(params + w * 3, u);
#pragma unroll
    for (int k = 0; k < 8; ++k) U1[w][k] = u[k];
  }
  __syncthreads();
  if (b >= Bn) return;

  cpx A00{0,0}, A01{0,0}, A10{0,0}, A11{0,0};   // accumulator
  cpx z00{1.f,0}, z01{0,0}, z10{0,0}, z11{0,0}; // zf (starts at e_(0,0))
  cpx p00{0,0}, p01{0,0}, p10{0,0}, p11{0,0};   // pending X pair
  float f0 = 1.f, f1 = 0.f;                     // all-I vector (real diagonal)

#pragma unroll
  for (int v = 0; v < 10; ++v) {
    float sn, cs; __sincosf(0.5f * xv[v], &sn, &cs);
    cpx g0 = {U1[v][0]*cs + U1[v][2]*sn, U1[v][1]*cs + U1[v][3]*sn};
    cpx g1 = {U1[v][4]*cs + U1[v][6]*sn, U1[v][5]*cs + U1[v][7]*sn};
    float n0 = g0.r*g0.r + g0.i*g0.i, n1 = g1.r*g1.r + g1.i*g1.i;
    const float xm00 = XM[v][0], xm11 = XM[v][1];
    const cpx xm01 = {XM[v][2], XM[v][3]};

    // ---- A: identity transfer (output is diagonal) ----
    cpx t100 = cadd(cjmul(g0, A00), cjmul(g1, A10));
    cpx t101 = cadd(cjmul(g0, A01), cjmul(g1, A11));
    cpx t110 = cadd(cjmul(g1, A00), cjmul(g0, A10));
    cpx t111 = cadd(cjmul(g1, A01), cjmul(g0, A11));
    cpx nA00 = cadd(cmul(g0, t100), cmul(g1, t101));
    cpx nA11 = cadd(cmul(g1, t110), cmul(g0, t111));
    cpx nA01{0,0}, nA10{0,0};

    // ---- complete pending X_{v-1}: apply T^{XM_v} to px, add with hw[10+v-1] ----
    if (v >= 1) {
      cpx s100 = cadd(cjmul(g0, p00), cjmul(g1, p10));
      cpx s101 = cadd(cjmul(g0, p01), cjmul(g1, p11));
      cpx s110 = cadd(cjmul(g1, p00), cjmul(g0, p10));
      cpx s111 = cadd(cjmul(g1, p01), cjmul(g0, p11));
      cpx q00 = cadd(cmul(g0, s100), cmul(g1, s101));
      cpx q01 = cadd(cmul(g1, s100), cmul(g0, s101));
      cpx q10 = cadd(cmul(g0, s110), cmul(g1, s111));
      cpx q11 = cadd(cmul(g1, s110), cmul(g0, s111));
      const float w = hw[10 + v - 1];
      nA00 = cadd(nA00, csc(q00, xm00 * w));
      nA11 = cadd(nA11, csc(q11, xm11 * w));
      nA01 = cadd(nA01, csc(cmul(xm01, q01), w));
      nA10 = cadd(nA10, csc(cmul(cconj(xm01), q10), w));
    }

    // ---- start X_v from f (real diagonal): px = XM .* S ----
    {
      cpx h01 = cjmul(g0, g1);                      // conj(g0)*g1
      float S00 = n0 * f0 + n1 * f1;
      float S11 = n1 * f0 + n0 * f1;
      cpx S01 = cadd(csc(h01, f0), csc(cconj(h01), f1));
      cpx S10 = cconj(S01);
      p00 = {S00 * xm00, 0.f};
      p11 = {S11 * xm11, 0.f};
      p01 = cmul(xm01, S01);
      p10 = cmul(cconj(xm01), S10);
    }

    // ---- zf: transfer with ZM_v, then add completed Z_v with hw[v] ----
    {
      const float zm00 = ZM[v][0], zm11 = ZM[v][1];
      const cpx zm01 = {ZM[v][2], ZM[v][3]};
      cpx r100 = cadd(cjmul(g0, z00), cjmul(g1, z10));
      cpx r101 = cadd(cjmul(g0, z01), cjmul(g1, z11));
      cpx r110 = cadd(cjmul(g1, z00), cjmul(g0, z10));
      cpx r111 = cadd(cjmul(g1, z01), cjmul(g0, z11));
      cpx y00 = cadd(cmul(g0, r100), cmul(g1, r101));
      cpx y01 = cadd(cmul(g1, r100), cmul(g0, r101));
      cpx y10 = cadd(cmul(g0, r110), cmul(g1, r111));
      cpx y11 = cadd(cmul(g1, r110), cmul(g0, r111));
      z00 = csc(y00, zm00); z11 = csc(y11, zm11);
      z01 = cmul(zm01, y01); z10 = cmul(cconj(zm01), y10);
      const float w = hw[v];
      nA00 = cadd(nA00, csc(z00, w)); nA01 = cadd(nA01, csc(z01, w));
      nA10 = cadd(nA10, csc(z10, w)); nA11 = cadd(nA11, csc(z11, w));
    }

    A00 = nA00; A01 = nA01; A10 = nA10; A11 = nA11;
    const float nf0 = n0 * f0 + n1 * f1;
    const float nf1 = n1 * f0 + n0 * f1;
    f0 = nf0; f1 = nf1;
  }

  // X_9 is single-wire: px after step 9 IS the complete feature.
  const float res = A00.r + A01.r + A10.r + A11.r
                  + hw[19] * (p00.r + p01.r + p10.r + p11.r)
                  + hb[0];
  out[b] = res;
}

extern "C" void kernel_launch(void* const* d_in, const int* in_sizes, int n_in,
                              void* d_out, int out_size, void* d_ws, size_t ws_size,
                              hipStream_t stream) {
  const float* x      = (const float*)d_in[0];
  const float* params = (const float*)d_in[1];
  const float* hw     = (const float*)d_in[2];
  const float* hb     = (const float*)d_in[3];
  float* out = (float*)d_out;
  const int B = in_sizes[0] / 10;
  const int blocks = (B + 63) / 64;  // one THREAD per sample, 64-thread blocks
  qreg_kernel<<<blocks, 64, 0, stream>>>(x, params, hw, hb, out, B);
}